// Round 16
// baseline (195.652 us; speedup 1.0000x reference)
//
#include <hip/hip_runtime.h>
#include <hip/hip_bf16.h>
#include <hip/hip_fp8.h>
#include <math.h>

typedef __attribute__((ext_vector_type(8))) __bf16 bf16x8;
typedef __attribute__((ext_vector_type(4))) __bf16 bf16x4;
typedef __attribute__((ext_vector_type(4))) float f32x4;
typedef __attribute__((ext_vector_type(4))) int i32x4;
typedef __attribute__((ext_vector_type(8))) int i32x8;

#define DIM 768
#define DFF 3072
#define HEADS 12
#define DKH 64
#define SEQ 1024
#define BATCH 8
#define ROWS (SEQ * BATCH)

#define GLD16(gp, lp)                                                      \
  __builtin_amdgcn_global_load_lds(                                        \
      (const __attribute__((address_space(1))) void*)(gp),                 \
      (__attribute__((address_space(3))) void*)(lp), 16, 0, 0)

__device__ __forceinline__ unsigned int pack4_e4m3(float a, float b, float c, float d) {
  __hip_fp8_e4m3 q0(a), q1(b), q2(c), q3(d);
  return (unsigned int)q0.__x | ((unsigned int)q1.__x << 8) |
         ((unsigned int)q2.__x << 16) | ((unsigned int)q3.__x << 24);
}

// ------- weight convert: qkv/proj -> bf16, fc1/fc2 -> fp8 e4m3 x16 -------
__global__ __launch_bounds__(256) void cvt4_kernel(const float* __restrict__ s0, int n0,
                                                   const float* __restrict__ s1, int n1,
                                                   const float* __restrict__ s2, int n2,
                                                   const float* __restrict__ s3, int n3,
                                                   __bf16* __restrict__ d0,
                                                   __bf16* __restrict__ d1,
                                                   unsigned char* __restrict__ d2,
                                                   unsigned char* __restrict__ d3) {
  int i0 = blockIdx.x * 256 + threadIdx.x;
  int st = gridDim.x * 256;
  const float* bsrc[2] = {s0, s1};
  __bf16* bdst[2] = {d0, d1};
  int bns[2] = {n0, n1};
#pragma unroll
  for (int t = 0; t < 2; ++t) {
    const f32x4* in = reinterpret_cast<const f32x4*>(bsrc[t]);
    bf16x4* out = reinterpret_cast<bf16x4*>(bdst[t]);
    for (int i = i0; i < bns[t]; i += st) {
      f32x4 v = in[i];
      bf16x4 o;
#pragma unroll
      for (int j = 0; j < 4; ++j) o[j] = (__bf16)v[j];
      out[i] = o;
    }
  }
  const float* fsrc[2] = {s2, s3};
  unsigned char* fdst[2] = {d2, d3};
  int fns[2] = {n2, n3};
#pragma unroll
  for (int t = 0; t < 2; ++t) {  // fp8 x16 (keeps weights out of e4m3 subnormal range)
    const f32x4* in = reinterpret_cast<const f32x4*>(fsrc[t]);
    unsigned int* out = reinterpret_cast<unsigned int*>(fdst[t]);
    for (int i = i0; i < fns[t]; i += st) {
      f32x4 v = in[i];
      out[i] = pack4_e4m3(v[0] * 16.f, v[1] * 16.f, v[2] * 16.f, v[3] * 16.f);
    }
  }
}

// ---------------- layernorm: fp32 in -> bf16 out (1 wave / row) ----------------
__global__ __launch_bounds__(256) void ln_kernel(const float* __restrict__ x,
                                                 const float* __restrict__ w,
                                                 const float* __restrict__ b,
                                                 __bf16* __restrict__ out) {
  int wid = threadIdx.x >> 6, lane = threadIdx.x & 63;
  int row = blockIdx.x * 4 + wid;
  const f32x4* xp = reinterpret_cast<const f32x4*>(x + (size_t)row * DIM);
  f32x4 v[3];
  float s1 = 0.f, s2 = 0.f;
#pragma unroll
  for (int i = 0; i < 3; ++i) {
    v[i] = xp[lane + i * 64];
#pragma unroll
    for (int c = 0; c < 4; ++c) { s1 += v[i][c]; s2 += v[i][c] * v[i][c]; }
  }
#pragma unroll
  for (int off = 1; off < 64; off <<= 1) {
    s1 += __shfl_xor(s1, off, 64);
    s2 += __shfl_xor(s2, off, 64);
  }
  float mu = s1 * (1.f / DIM);
  float var = s2 * (1.f / DIM) - mu * mu;
  float rs = rsqrtf(var + 1e-5f);
  const f32x4* wp = reinterpret_cast<const f32x4*>(w);
  const f32x4* bp = reinterpret_cast<const f32x4*>(b);
  __bf16* op = out + (size_t)row * DIM;
#pragma unroll
  for (int i = 0; i < 3; ++i) {
    int c4 = lane + i * 64;
    f32x4 wv = wp[c4], bv = bp[c4];
    bf16x4 ov;
#pragma unroll
    for (int c = 0; c < 4; ++c) ov[c] = (__bf16)((v[i][c] - mu) * rs * wv[c] + bv[c]);
    *reinterpret_cast<bf16x4*>(&op[c4 * 4]) = ov;
  }
}

// ---------------- layernorm: fp32 in -> fp8 e4m3 out (for FC1's fp8 path) ----------------
__global__ __launch_bounds__(256) void ln_f8_kernel(const float* __restrict__ x,
                                                    const float* __restrict__ w,
                                                    const float* __restrict__ b,
                                                    unsigned char* __restrict__ out) {
  int wid = threadIdx.x >> 6, lane = threadIdx.x & 63;
  int row = blockIdx.x * 4 + wid;
  const f32x4* xp = reinterpret_cast<const f32x4*>(x + (size_t)row * DIM);
  f32x4 v[3];
  float s1 = 0.f, s2 = 0.f;
#pragma unroll
  for (int i = 0; i < 3; ++i) {
    v[i] = xp[lane + i * 64];
#pragma unroll
    for (int c = 0; c < 4; ++c) { s1 += v[i][c]; s2 += v[i][c] * v[i][c]; }
  }
#pragma unroll
  for (int off = 1; off < 64; off <<= 1) {
    s1 += __shfl_xor(s1, off, 64);
    s2 += __shfl_xor(s2, off, 64);
  }
  float mu = s1 * (1.f / DIM);
  float var = s2 * (1.f / DIM) - mu * mu;
  float rs = rsqrtf(var + 1e-5f);
  const f32x4* wp = reinterpret_cast<const f32x4*>(w);
  const f32x4* bp = reinterpret_cast<const f32x4*>(b);
  unsigned int* op = reinterpret_cast<unsigned int*>(out + (size_t)row * DIM);
#pragma unroll
  for (int i = 0; i < 3; ++i) {
    int c4 = lane + i * 64;
    f32x4 wv = wp[c4], bv = bp[c4];
    float o0 = (v[i][0] - mu) * rs * wv[0] + bv[0];
    float o1 = (v[i][1] - mu) * rs * wv[1] + bv[1];
    float o2 = (v[i][2] - mu) * rs * wv[2] + bv[2];
    float o3 = (v[i][3] - mu) * rs * wv[3] + bv[3];
    op[c4] = pack4_e4m3(o0, o1, o2, o3);
  }
}

// ---------------- NT GEMM: BN=64, SINGLE 24KB buffer (m97 structure) -> 4 blocks/CU ---------
// r9-proven config. Hint (256,4): VGPR cap 128 >= natural 68 -> no squeeze.
// r10/r12 lesson: ANY waves/EU hint > 4 at 256 threads forces sub-natural VGPR and spills.
template <int EPI, int BN, int DBUF>
__global__ __launch_bounds__(256, 4) void gemm_nt(const __bf16* __restrict__ A,
                                                  const __bf16* __restrict__ B,
                                                  const float* __restrict__ bias,
                                                  const float* __restrict__ resid,
                                                  __bf16* __restrict__ vt,
                                                  void* __restrict__ Cout,
                                                  int M, int N, int K) {
  constexpr int NBUF = DBUF ? 2 : 1;
  constexpr int MF = (BN == 128) ? 4 : 2;
  static_assert(BN == 64, "geometry assumes BN=64");
  __shared__ __bf16 As[NBUF * 128 * 64];
  __shared__ __bf16 Bs[NBUF * BN * 64];
  int tid = threadIdx.x;
  int bm = blockIdx.x, bn = blockIdx.y;
  int wid = tid >> 6, lane = tid & 63;
  int l15 = lane & 15, l4 = lane >> 4;
  int rowb = wid * 32;
  int colb = 0;

  f32x4 acc[MF][4] = {};

  auto stage = [&](int buf, int kt) {
    __bf16* Ab = As + buf * 128 * 64;
    __bf16* Bb = Bs + buf * BN * 64;
#pragma unroll
    for (int r = 0; r < 4; ++r) {
      int c0 = (r * 4 + wid) * 64;
      int c = c0 + lane;
      int row = c >> 3;
      int colE = ((c & 7) ^ (row & 7)) * 8;
      GLD16(&A[(size_t)(bm * 128 + row) * K + kt + colE], &Ab[c0 * 8]);
    }
#pragma unroll
    for (int r = 0; r < BN / 32; ++r) {
      int c0 = (r * 4 + wid) * 64;
      int c = c0 + lane;
      int row = c >> 3;
      int colE = ((c & 7) ^ (row & 7)) * 8;
      GLD16(&B[(size_t)(bn * BN + row) * K + kt + colE], &Bb[c0 * 8]);
    }
  };

  auto compute = [&](int buf) {
    const __bf16* Ab = As + buf * 128 * 64;
    const __bf16* Bb = Bs + buf * BN * 64;
#pragma unroll
    for (int kc = 0; kc < 2; ++kc) {
      int cswz = ((kc * 4 + l4) ^ (l15 & 7)) * 8;
      bf16x8 af[MF], bfr[4];
#pragma unroll
      for (int m = 0; m < MF; ++m)
        af[m] = *reinterpret_cast<const bf16x8*>(&Ab[(rowb + m * 16 + l15) * 64 + cswz]);
#pragma unroll
      for (int n = 0; n < 4; ++n)
        bfr[n] = *reinterpret_cast<const bf16x8*>(&Bb[(colb + n * 16 + l15) * 64 + cswz]);
#pragma unroll
      for (int m = 0; m < MF; ++m)
#pragma unroll
        for (int n = 0; n < 4; ++n)
          acc[m][n] = __builtin_amdgcn_mfma_f32_16x16x32_bf16(af[m], bfr[n], acc[m][n], 0, 0, 0);
    }
  };

  if constexpr (DBUF) {
    stage(0, 0);
    int cur = 0;
    for (int kt = 0; kt < K; kt += 64) {
      if (kt + 64 < K) {
        stage(cur ^ 1, kt + 64);
        asm volatile("s_waitcnt vmcnt(6)" ::: "memory");
      } else {
        asm volatile("s_waitcnt vmcnt(0)" ::: "memory");
      }
      __builtin_amdgcn_s_barrier();
      compute(cur);
      asm volatile("s_waitcnt lgkmcnt(0)" ::: "memory");
      __builtin_amdgcn_s_barrier();
      cur ^= 1;
    }
  } else {
    // m97 single-buffer loop: __syncthreads drains vmcnt/lgkm (RAW + WAR).
    for (int kt = 0; kt < K; kt += 64) {
      __syncthreads();
      stage(0, kt);
      __syncthreads();
      compute(0);
    }
  }

#pragma unroll
  for (int m = 0; m < MF; ++m)
#pragma unroll
    for (int n = 0; n < 4; ++n) {
      int row0 = bm * 128 + rowb + m * 16 + l4 * 4;
      int col = bn * BN + colb + n * 16 + l15;
      float bc = bias[col];
      if (EPI == 0 && col >= 2 * DIM) {
        int h = (col - 2 * DIM) >> 6, dk = (col - 2 * DIM) & 63;
        int b = row0 >> 10, tok = row0 & 1023;
        bf16x4 pk;
#pragma unroll
        for (int j = 0; j < 4; ++j) pk[j] = (__bf16)(acc[m][n][j] + bc);
        *reinterpret_cast<bf16x4*>(
            &vt[(size_t)((b * HEADS + h) * DKH + dk) * SEQ + tok]) = pk;
      } else {
#pragma unroll
        for (int j = 0; j < 4; ++j) {
          float v = acc[m][n][j] + bc;
          size_t idx = (size_t)(row0 + j) * N + col;
          if (EPI == 0) {
            ((__bf16*)Cout)[idx] = (__bf16)v;
          } else {
            ((float*)Cout)[idx] = v + resid[idx];
          }
        }
      }
    }
}

// ---------------- fp8 GEMM, MX-scaled K=128 MFMA, BK=128, SINGLE 24KB buffer ----------------
// A,B in e4m3. LDS 24KB; hint (256,4) -> natural VGPR 56, 4 blk/CU, no spill.
// r13 bank-conflict fix (confirmed: fp8 dispatches left the top-5): chunk j=2a+p stored at
// slot (a+4p)^(r&7) -> read slots l4^s7 and (l4^s7)^4, matching the proven bf16 pattern.
// EPI=0 (FC1): A unscaled, B x16 -> acc*0.0625, +bias, GELU, out = e4m3 x16 (bytes).
// EPI=1 (FC2): A x16, B x16 -> acc/256, +bias, +resid, out = fp32.
template <int EPI>
__global__ __launch_bounds__(256, 4) void gemm_fp8(const unsigned char* __restrict__ A,
                                                   const unsigned char* __restrict__ B,
                                                   const float* __restrict__ bias,
                                                   const float* __restrict__ resid,
                                                   void* __restrict__ Cout,
                                                   int M, int N, int K) {
  __shared__ unsigned char As[128 * 128];   // 16KB
  __shared__ unsigned char Bs[64 * 128];    // 8KB
  int tid = threadIdx.x;
  int bm = blockIdx.x, bn = blockIdx.y;
  int wid = tid >> 6, lane = tid & 63;
  int l15 = lane & 15, l4 = lane >> 4;
  int rowb = wid * 32;

  f32x4 acc[2][4] = {};

  // slot s of row r holds global chunk j = sigma^-1(s ^ (r&7)), sigma(2a+p)=a+4p.
  auto stage = [&](int kt) {
#pragma unroll
    for (int r = 0; r < 4; ++r) {       // A: 128 rows x 8 chunks = 1024
      int c0 = (r * 4 + wid) * 64;
      int c = c0 + lane;
      int row = c >> 3;
      int v = (c & 7) ^ (row & 7);
      int j = 2 * (v & 3) + (v >> 2);
      GLD16(&A[(size_t)(bm * 128 + row) * K + kt + j * 16], &As[c0 * 16]);
    }
#pragma unroll
    for (int r = 0; r < 2; ++r) {       // B: 64 rows x 8 chunks = 512
      int c0 = (r * 4 + wid) * 64;
      int c = c0 + lane;
      int row = c >> 3;
      int v = (c & 7) ^ (row & 7);
      int j = 2 * (v & 3) + (v >> 2);
      GLD16(&B[(size_t)(bn * 64 + row) * K + kt + j * 16], &Bs[c0 * 16]);
    }
  };

  // lane's 32 K-bytes (chunks 2*l4, 2*l4+1) live at slots l4^s7 and (l4^s7)^4.
  auto ld32 = [&](const unsigned char* base, int row) -> i32x8 {
    int off = (l4 ^ (l15 & 7)) * 16;
    i32x8 r;
    *reinterpret_cast<i32x4*>(&r) =
        *reinterpret_cast<const i32x4*>(&base[row * 128 + off]);
    *(reinterpret_cast<i32x4*>(&r) + 1) =
        *reinterpret_cast<const i32x4*>(&base[row * 128 + (off ^ 64)]);
    return r;
  };

  auto compute = [&]() {
    i32x8 af[2], bfr[4];
#pragma unroll
    for (int m = 0; m < 2; ++m) af[m] = ld32(As, rowb + m * 16 + l15);
#pragma unroll
    for (int n = 0; n < 4; ++n) bfr[n] = ld32(Bs, n * 16 + l15);
#pragma unroll
    for (int m = 0; m < 2; ++m)
#pragma unroll
      for (int n = 0; n < 4; ++n)
        acc[m][n] = __builtin_amdgcn_mfma_scale_f32_16x16x128_f8f6f4(
            af[m], bfr[n], acc[m][n], 0, 0,          // cbsz=0 (e4m3), blgp=0 (e4m3)
            0, 0x7F7F7F7F,                           // opsel_a, scale_a = 1.0 (e8m0 127)
            0, 0x7F7F7F7F);                          // opsel_b, scale_b = 1.0
  };

  for (int kt = 0; kt < K; kt += 128) {
    __syncthreads();               // WAR: all waves done reading previous tile
    stage(kt);
    __syncthreads();               // RAW: drains vmcnt -> tile landed for all waves
    compute();
  }

#pragma unroll
  for (int m = 0; m < 2; ++m)
#pragma unroll
    for (int n = 0; n < 4; ++n) {
      int row0 = bm * 128 + rowb + m * 16 + l4 * 4;
      int col = bn * 64 + n * 16 + l15;
      float bc = bias[col];
#pragma unroll
      for (int j = 0; j < 4; ++j) {
        if (EPI == 0) {
          float v = acc[m][n][j] * 0.0625f + bc;   // undo weight x16
          float z = 1.59576912f * (v + 0.044715f * v * v * v);
          float tt = __expf(fminf(z, 80.f));
          float g = v * __fdividef(tt, tt + 1.0f);
          // emit e4m3 x16 for the fp8 FC2 path (|g|<=~3 -> x16 <= 48 << 448 max)
          ((unsigned char*)Cout)[(size_t)(row0 + j) * N + col] =
              __hip_fp8_e4m3(g * 16.f).__x;
        } else {
          size_t idx = (size_t)(row0 + j) * N + col;
          ((float*)Cout)[idx] = acc[m][n][j] * (1.f / 256.f) + bc + resid[idx];
        }
      }
    }
}

// ---------------- flash attention: 128-row Q tiles, TWO KV tiles per barrier pair -----------
// r15: revert r14's Q-split (doubled staging work, regressed). Keep r13 geometry (768 blocks,
// 3/CU grid cap) but halve the barrier-slot count: stage K/V for kv tiles i and i+1 into two
// buffers in ONE __syncthreads pair, then compute both sequentially (registers reused; the
// P round-trip is per-wave-private LDS, in-order DS ops make tile1's P-write safe after
// tile0's P-read). Slots 16 -> 8 at identical staging bytes and residency:
// LDS = 2x16KB (K/V) + 18KB (Ps) = 50.8KB; 3 x 50.8 = 152.4 <= 160KB.
__global__ __launch_bounds__(256, 3) void attn_kernel(const __bf16* __restrict__ qkv,
                                                      const __bf16* __restrict__ vt,
                                                      __bf16* __restrict__ out) {
  int bid = blockIdx.x;
  int xcd = bid & 7, kk0 = bid >> 3;     // 96 blocks per XCD
  int bh = (kk0 >> 3) * 8 + xcd;         // 12 heads per XCD
  int qt = kk0 & 7;
  int b = bh / HEADS, h = bh % HEADS;
  int tid = threadIdx.x, wid = tid >> 6, lane = tid & 63;
  int l15 = lane & 15, l4 = lane >> 4;
  int qr0 = qt * 128 + wid * 32;
  const size_t rs = 3 * DIM;
  const __bf16* Qb = qkv + (size_t)(b * SEQ) * rs + h * DKH;
  const __bf16* Kb = Qb + DIM;
  const __bf16* Vb = vt + (size_t)bh * DKH * SEQ;

  __shared__ __bf16 Ks[2][64 * 64];
  __shared__ __bf16 Vs[2][64 * 64];
  __shared__ __bf16 Ps[4][32][72];
  __bf16(*Psw)[72] = Ps[wid];

  bf16x8 qf[2][2];
#pragma unroll
  for (int m = 0; m < 2; ++m)
#pragma unroll
    for (int kc = 0; kc < 2; ++kc) {
      bf16x8 t = *reinterpret_cast<const bf16x8*>(
          &Qb[(size_t)(qr0 + m * 16 + l15) * rs + kc * 32 + l4 * 8]);
#pragma unroll
      for (int e = 0; e < 8; ++e) t[e] = (__bf16)((float)t[e] * 0.125f);
      qf[m][kc] = t;
    }

  f32x4 o[2][4] = {};
  f32x4 lsum[2] = {};

  for (int kv0 = 0; kv0 < SEQ; kv0 += 128) {
    __syncthreads();               // WAR: all waves done reading both buffers
#pragma unroll
    for (int hf = 0; hf < 2; ++hf) {
      int kvb = kv0 + hf * 64;
#pragma unroll
      for (int cc = 0; cc < 2; ++cc) {
        int c0 = (wid * 2 + cc) * 64;
        int c = c0 + lane;
        int row = c >> 3;
        int sb = (c & 7) * 16;
        int pkc = sb ^ (((row >> 2) & 7) << 4);
        GLD16(&Kb[(size_t)(kvb + row) * rs + (pkc >> 1)], &Ks[hf][c0 * 8]);
        int pvc = sb ^ ((row & 7) << 4);
        GLD16(&Vb[(size_t)row * SEQ + kvb + (pvc >> 1)], &Vs[hf][c0 * 8]);
      }
    }
    __syncthreads();               // RAW: both tiles landed

#pragma unroll
    for (int hf = 0; hf < 2; ++hf) {
      const __bf16* Ksh = Ks[hf];
      const __bf16* Vsh = Vs[hf];

      bf16x8 kb[4][2];
#pragma unroll
      for (int nf = 0; nf < 4; ++nf)
#pragma unroll
        for (int kc = 0; kc < 2; ++kc) {
          int row = 4 * l15 + nf;
          int col = (kc * 64 + l4 * 16) ^ ((l15 & 7) << 4);
          kb[nf][kc] = *reinterpret_cast<const bf16x8*>(&Ksh[row * 64 + (col >> 1)]);
        }
      f32x4 s[2][4] = {};
#pragma unroll
      for (int m = 0; m < 2; ++m)
#pragma unroll
        for (int nf = 0; nf < 4; ++nf)
#pragma unroll
          for (int kc = 0; kc < 2; ++kc)
            s[m][nf] = __builtin_amdgcn_mfma_f32_16x16x32_bf16(qf[m][kc], kb[nf][kc], s[m][nf], 0, 0, 0);

      bf16x8 vf[4][2];
#pragma unroll
      for (int d = 0; d < 4; ++d)
#pragma unroll
        for (int kc = 0; kc < 2; ++kc) {
          int row = d * 16 + l15;
          int col = (kc * 64 + l4 * 16) ^ ((l15 & 7) << 4);
          vf[d][kc] = *reinterpret_cast<const bf16x8*>(&Vsh[row * 64 + (col >> 1)]);
        }

#pragma unroll
      for (int m = 0; m < 2; ++m)
#pragma unroll
        for (int j = 0; j < 4; ++j) {
          bf16x4 pk;
          float ss = 0.f;
#pragma unroll
          for (int nf = 0; nf < 4; ++nf) {
            float p = __expf(s[m][nf][j]);
            ss += p;
            pk[nf] = (__bf16)p;
          }
          lsum[m][j] += ss;
          *reinterpret_cast<bf16x4*>(&Psw[m * 16 + l4 * 4 + j][l15 * 4]) = pk;
        }
      asm volatile("s_waitcnt lgkmcnt(0)" ::: "memory");
      __builtin_amdgcn_sched_barrier(0);

      bf16x8 pf[2][2];
#pragma unroll
      for (int m = 0; m < 2; ++m)
#pragma unroll
        for (int kc = 0; kc < 2; ++kc)
          pf[m][kc] = *reinterpret_cast<const bf16x8*>(&Psw[m * 16 + l15][kc * 32 + l4 * 8]);
#pragma unroll
      for (int m = 0; m < 2; ++m)
#pragma unroll
        for (int d = 0; d < 4; ++d)
#pragma unroll
          for (int kc = 0; kc < 2; ++kc)
            o[m][d] = __builtin_amdgcn_mfma_f32_16x16x32_bf16(pf[m][kc], vf[d][kc], o[m][d], 0, 0, 0);
    }
  }

#pragma unroll
  for (int off = 1; off < 16; off <<= 1)
#pragma unroll
    for (int m = 0; m < 2; ++m)
#pragma unroll
      for (int j = 0; j < 4; ++j) lsum[m][j] += __shfl_xor(lsum[m][j], off, 64);

  __bf16* op = out + (size_t)(b * SEQ) * DIM + h * DKH;
#pragma unroll
  for (int m = 0; m < 2; ++m)
#pragma unroll
    for (int j = 0; j < 4; ++j) {
      float rl = 1.f / lsum[m][j];
      int row = qr0 + m * 16 + l4 * 4 + j;
#pragma unroll
      for (int d = 0; d < 4; ++d)
        op[(size_t)row * DIM + d * 16 + l15] = (__bf16)(o[m][d][j] * rl);
    }
}

extern "C" void kernel_launch(void* const* d_in, const int* in_sizes, int n_in,
                              void* d_out, int out_size, void* d_ws, size_t ws_size,
                              hipStream_t stream) {
  const float* x      = (const float*)d_in[0];
  const float* ln1_w  = (const float*)d_in[1];
  const float* ln1_b  = (const float*)d_in[2];
  const float* qkv_w  = (const float*)d_in[3];
  const float* qkv_b  = (const float*)d_in[4];
  const float* proj_w = (const float*)d_in[5];
  const float* proj_b = (const float*)d_in[6];
  const float* ln2_w  = (const float*)d_in[7];
  const float* ln2_b  = (const float*)d_in[8];
  const float* fc1_w  = (const float*)d_in[9];
  const float* fc1_b  = (const float*)d_in[10];
  const float* fc2_w  = (const float*)d_in[11];
  const float* fc2_b  = (const float*)d_in[12];

  char* ws = (char*)d_ws;
  size_t o = 0;
  __bf16* qkvw_bf = (__bf16*)(ws + o); o += (size_t)3 * DIM * DIM * 2;
  __bf16* projw_bf = (__bf16*)(ws + o); o += (size_t)DIM * DIM * 2;
  unsigned char* fc1w_f8 = (unsigned char*)(ws + o); o += (size_t)DFF * DIM;
  unsigned char* fc2w_f8 = (unsigned char*)(ws + o); o += (size_t)DIM * DFF;
  __bf16* h_bf    = (__bf16*)(ws + o); o += (size_t)ROWS * DIM * 2;
  float*  x1      = (float*)(ws + o);  o += (size_t)ROWS * DIM * 4;
  __bf16* qkv_bf  = (__bf16*)(ws + o); o += (size_t)ROWS * 3 * DIM * 2;
  __bf16* attn_bf = (__bf16*)(ws + o); o += (size_t)ROWS * DIM * 2;
  unsigned char* ff_f8 = (unsigned char*)qkv_bf;  // FC1 fp8 out aliases dead qkv region
  __bf16* vtp     = (__bf16*)x1;                  // V^T aliases x1 (dead until proj writes it)
  unsigned char* h_f8 = (unsigned char*)h_bf;     // LN2 fp8 out reuses h (LN1 out dead by then)

  // 1. weights (qkv/proj -> bf16, fc1/fc2 -> fp8 x16)
  cvt4_kernel<<<2048, 256, 0, stream>>>(
      qkv_w, 3 * DIM * DIM / 4, proj_w, DIM * DIM / 4,
      fc1_w, DFF * DIM / 4, fc2_w, DIM * DFF / 4,
      qkvw_bf, projw_bf, fc1w_f8, fc2w_f8);

  // 2. LN1
  ln_kernel<<<ROWS / 4, 256, 0, stream>>>(x, ln1_w, ln1_b, h_bf);
  // 3. QKV = h @ qkv_w^T + b   (V stored transposed into vtp)
  gemm_nt<0, 64, 0><<<dim3(ROWS / 128, 3 * DIM / 64), 256, 0, stream>>>(
      h_bf, qkvw_bf, qkv_b, nullptr, vtp, qkv_bf, ROWS, 3 * DIM, DIM);
  // 4. attention (768 XCD-swizzled blocks, paired KV tiles)
  attn_kernel<<<dim3(8 * BATCH * HEADS), 256, 0, stream>>>(qkv_bf, vtp, attn_bf);
  // 5. x1 = x + attn @ proj_w^T + b
  gemm_nt<2, 64, 0><<<dim3(ROWS / 128, DIM / 64), 256, 0, stream>>>(
      attn_bf, projw_bf, proj_b, x, nullptr, x1, ROWS, DIM, DIM);
  // 6. LN2 -> fp8
  ln_f8_kernel<<<ROWS / 4, 256, 0, stream>>>(x1, ln2_w, ln2_b, h_f8);
  // 7. ff = gelu(h2 @ fc1_w^T + b) -> e4m3 x16  (fp8 MX path, BK=128)
  gemm_fp8<0><<<dim3(ROWS / 128, DFF / 64), 256, 0, stream>>>(
      h_f8, fc1w_f8, fc1_b, nullptr, ff_f8, ROWS, DFF, DIM);
  // 8. out = x1 + ff @ fc2_w^T + b  (fp8 MX path, K=3072, 24 K-steps)
  gemm_fp8<1><<<dim3(ROWS / 128, DIM / 64), 256, 0, stream>>>(
      ff_f8, fc2w_f8, fc2_b, x1, (float*)d_out, ROWS, DIM, DFF);
}

// Round 17
// 181.671 us; speedup vs baseline: 1.0770x; 1.0770x over previous
//
#include <hip/hip_runtime.h>
#include <hip/hip_bf16.h>
#include <hip/hip_fp8.h>
#include <math.h>

typedef __attribute__((ext_vector_type(8))) __bf16 bf16x8;
typedef __attribute__((ext_vector_type(4))) __bf16 bf16x4;
typedef __attribute__((ext_vector_type(4))) float f32x4;
typedef __attribute__((ext_vector_type(4))) int i32x4;
typedef __attribute__((ext_vector_type(8))) int i32x8;

#define DIM 768
#define DFF 3072
#define HEADS 12
#define DKH 64
#define SEQ 1024
#define BATCH 8
#define ROWS (SEQ * BATCH)

#define GLD16(gp, lp)                                                      \
  __builtin_amdgcn_global_load_lds(                                        \
      (const __attribute__((address_space(1))) void*)(gp),                 \
      (__attribute__((address_space(3))) void*)(lp), 16, 0, 0)

__device__ __forceinline__ unsigned int pack4_e4m3(float a, float b, float c, float d) {
  __hip_fp8_e4m3 q0(a), q1(b), q2(c), q3(d);
  return (unsigned int)q0.__x | ((unsigned int)q1.__x << 8) |
         ((unsigned int)q2.__x << 16) | ((unsigned int)q3.__x << 24);
}

// ------- weight convert: qkv/proj -> bf16, fc1/fc2 -> fp8 e4m3 x16 -------
__global__ __launch_bounds__(256) void cvt4_kernel(const float* __restrict__ s0, int n0,
                                                   const float* __restrict__ s1, int n1,
                                                   const float* __restrict__ s2, int n2,
                                                   const float* __restrict__ s3, int n3,
                                                   __bf16* __restrict__ d0,
                                                   __bf16* __restrict__ d1,
                                                   unsigned char* __restrict__ d2,
                                                   unsigned char* __restrict__ d3) {
  int i0 = blockIdx.x * 256 + threadIdx.x;
  int st = gridDim.x * 256;
  const float* bsrc[2] = {s0, s1};
  __bf16* bdst[2] = {d0, d1};
  int bns[2] = {n0, n1};
#pragma unroll
  for (int t = 0; t < 2; ++t) {
    const f32x4* in = reinterpret_cast<const f32x4*>(bsrc[t]);
    bf16x4* out = reinterpret_cast<bf16x4*>(bdst[t]);
    for (int i = i0; i < bns[t]; i += st) {
      f32x4 v = in[i];
      bf16x4 o;
#pragma unroll
      for (int j = 0; j < 4; ++j) o[j] = (__bf16)v[j];
      out[i] = o;
    }
  }
  const float* fsrc[2] = {s2, s3};
  unsigned char* fdst[2] = {d2, d3};
  int fns[2] = {n2, n3};
#pragma unroll
  for (int t = 0; t < 2; ++t) {  // fp8 x16 (keeps weights out of e4m3 subnormal range)
    const f32x4* in = reinterpret_cast<const f32x4*>(fsrc[t]);
    unsigned int* out = reinterpret_cast<unsigned int*>(fdst[t]);
    for (int i = i0; i < fns[t]; i += st) {
      f32x4 v = in[i];
      out[i] = pack4_e4m3(v[0] * 16.f, v[1] * 16.f, v[2] * 16.f, v[3] * 16.f);
    }
  }
}

// ---------------- layernorm: fp32 in -> bf16 out (1 wave / row) ----------------
__global__ __launch_bounds__(256) void ln_kernel(const float* __restrict__ x,
                                                 const float* __restrict__ w,
                                                 const float* __restrict__ b,
                                                 __bf16* __restrict__ out) {
  int wid = threadIdx.x >> 6, lane = threadIdx.x & 63;
  int row = blockIdx.x * 4 + wid;
  const f32x4* xp = reinterpret_cast<const f32x4*>(x + (size_t)row * DIM);
  f32x4 v[3];
  float s1 = 0.f, s2 = 0.f;
#pragma unroll
  for (int i = 0; i < 3; ++i) {
    v[i] = xp[lane + i * 64];
#pragma unroll
    for (int c = 0; c < 4; ++c) { s1 += v[i][c]; s2 += v[i][c] * v[i][c]; }
  }
#pragma unroll
  for (int off = 1; off < 64; off <<= 1) {
    s1 += __shfl_xor(s1, off, 64);
    s2 += __shfl_xor(s2, off, 64);
  }
  float mu = s1 * (1.f / DIM);
  float var = s2 * (1.f / DIM) - mu * mu;
  float rs = rsqrtf(var + 1e-5f);
  const f32x4* wp = reinterpret_cast<const f32x4*>(w);
  const f32x4* bp = reinterpret_cast<const f32x4*>(b);
  __bf16* op = out + (size_t)row * DIM;
#pragma unroll
  for (int i = 0; i < 3; ++i) {
    int c4 = lane + i * 64;
    f32x4 wv = wp[c4], bv = bp[c4];
    bf16x4 ov;
#pragma unroll
    for (int c = 0; c < 4; ++c) ov[c] = (__bf16)((v[i][c] - mu) * rs * wv[c] + bv[c]);
    *reinterpret_cast<bf16x4*>(&op[c4 * 4]) = ov;
  }
}

// ---------------- layernorm: fp32 in -> fp8 e4m3 out (for FC1's fp8 path) ----------------
__global__ __launch_bounds__(256) void ln_f8_kernel(const float* __restrict__ x,
                                                    const float* __restrict__ w,
                                                    const float* __restrict__ b,
                                                    unsigned char* __restrict__ out) {
  int wid = threadIdx.x >> 6, lane = threadIdx.x & 63;
  int row = blockIdx.x * 4 + wid;
  const f32x4* xp = reinterpret_cast<const f32x4*>(x + (size_t)row * DIM);
  f32x4 v[3];
  float s1 = 0.f, s2 = 0.f;
#pragma unroll
  for (int i = 0; i < 3; ++i) {
    v[i] = xp[lane + i * 64];
#pragma unroll
    for (int c = 0; c < 4; ++c) { s1 += v[i][c]; s2 += v[i][c] * v[i][c]; }
  }
#pragma unroll
  for (int off = 1; off < 64; off <<= 1) {
    s1 += __shfl_xor(s1, off, 64);
    s2 += __shfl_xor(s2, off, 64);
  }
  float mu = s1 * (1.f / DIM);
  float var = s2 * (1.f / DIM) - mu * mu;
  float rs = rsqrtf(var + 1e-5f);
  const f32x4* wp = reinterpret_cast<const f32x4*>(w);
  const f32x4* bp = reinterpret_cast<const f32x4*>(b);
  unsigned int* op = reinterpret_cast<unsigned int*>(out + (size_t)row * DIM);
#pragma unroll
  for (int i = 0; i < 3; ++i) {
    int c4 = lane + i * 64;
    f32x4 wv = wp[c4], bv = bp[c4];
    float o0 = (v[i][0] - mu) * rs * wv[0] + bv[0];
    float o1 = (v[i][1] - mu) * rs * wv[1] + bv[1];
    float o2 = (v[i][2] - mu) * rs * wv[2] + bv[2];
    float o3 = (v[i][3] - mu) * rs * wv[3] + bv[3];
    op[c4] = pack4_e4m3(o0, o1, o2, o3);
  }
}

// ---------------- NT GEMM: BN=64, SINGLE 24KB buffer (m97 structure) -> 4 blocks/CU ---------
// r9-proven config. Hint (256,4): VGPR cap 128 >= natural 68 -> no squeeze.
// r10/r12 lesson: ANY waves/EU hint > 4 at 256 threads forces sub-natural VGPR and spills.
template <int EPI, int BN, int DBUF>
__global__ __launch_bounds__(256, 4) void gemm_nt(const __bf16* __restrict__ A,
                                                  const __bf16* __restrict__ B,
                                                  const float* __restrict__ bias,
                                                  const float* __restrict__ resid,
                                                  __bf16* __restrict__ vt,
                                                  void* __restrict__ Cout,
                                                  int M, int N, int K) {
  constexpr int NBUF = DBUF ? 2 : 1;
  constexpr int MF = (BN == 128) ? 4 : 2;
  static_assert(BN == 64, "geometry assumes BN=64");
  __shared__ __bf16 As[NBUF * 128 * 64];
  __shared__ __bf16 Bs[NBUF * BN * 64];
  int tid = threadIdx.x;
  int bm = blockIdx.x, bn = blockIdx.y;
  int wid = tid >> 6, lane = tid & 63;
  int l15 = lane & 15, l4 = lane >> 4;
  int rowb = wid * 32;
  int colb = 0;

  f32x4 acc[MF][4] = {};

  auto stage = [&](int buf, int kt) {
    __bf16* Ab = As + buf * 128 * 64;
    __bf16* Bb = Bs + buf * BN * 64;
#pragma unroll
    for (int r = 0; r < 4; ++r) {
      int c0 = (r * 4 + wid) * 64;
      int c = c0 + lane;
      int row = c >> 3;
      int colE = ((c & 7) ^ (row & 7)) * 8;
      GLD16(&A[(size_t)(bm * 128 + row) * K + kt + colE], &Ab[c0 * 8]);
    }
#pragma unroll
    for (int r = 0; r < BN / 32; ++r) {
      int c0 = (r * 4 + wid) * 64;
      int c = c0 + lane;
      int row = c >> 3;
      int colE = ((c & 7) ^ (row & 7)) * 8;
      GLD16(&B[(size_t)(bn * BN + row) * K + kt + colE], &Bb[c0 * 8]);
    }
  };

  auto compute = [&](int buf) {
    const __bf16* Ab = As + buf * 128 * 64;
    const __bf16* Bb = Bs + buf * BN * 64;
#pragma unroll
    for (int kc = 0; kc < 2; ++kc) {
      int cswz = ((kc * 4 + l4) ^ (l15 & 7)) * 8;
      bf16x8 af[MF], bfr[4];
#pragma unroll
      for (int m = 0; m < MF; ++m)
        af[m] = *reinterpret_cast<const bf16x8*>(&Ab[(rowb + m * 16 + l15) * 64 + cswz]);
#pragma unroll
      for (int n = 0; n < 4; ++n)
        bfr[n] = *reinterpret_cast<const bf16x8*>(&Bb[(colb + n * 16 + l15) * 64 + cswz]);
#pragma unroll
      for (int m = 0; m < MF; ++m)
#pragma unroll
        for (int n = 0; n < 4; ++n)
          acc[m][n] = __builtin_amdgcn_mfma_f32_16x16x32_bf16(af[m], bfr[n], acc[m][n], 0, 0, 0);
    }
  };

  if constexpr (DBUF) {
    stage(0, 0);
    int cur = 0;
    for (int kt = 0; kt < K; kt += 64) {
      if (kt + 64 < K) {
        stage(cur ^ 1, kt + 64);
        asm volatile("s_waitcnt vmcnt(6)" ::: "memory");
      } else {
        asm volatile("s_waitcnt vmcnt(0)" ::: "memory");
      }
      __builtin_amdgcn_s_barrier();
      compute(cur);
      asm volatile("s_waitcnt lgkmcnt(0)" ::: "memory");
      __builtin_amdgcn_s_barrier();
      cur ^= 1;
    }
  } else {
    // m97 single-buffer loop: __syncthreads drains vmcnt/lgkm (RAW + WAR).
    for (int kt = 0; kt < K; kt += 64) {
      __syncthreads();
      stage(0, kt);
      __syncthreads();
      compute(0);
    }
  }

#pragma unroll
  for (int m = 0; m < MF; ++m)
#pragma unroll
    for (int n = 0; n < 4; ++n) {
      int row0 = bm * 128 + rowb + m * 16 + l4 * 4;
      int col = bn * BN + colb + n * 16 + l15;
      float bc = bias[col];
      if (EPI == 0 && col >= 2 * DIM) {
        int h = (col - 2 * DIM) >> 6, dk = (col - 2 * DIM) & 63;
        int b = row0 >> 10, tok = row0 & 1023;
        bf16x4 pk;
#pragma unroll
        for (int j = 0; j < 4; ++j) pk[j] = (__bf16)(acc[m][n][j] + bc);
        *reinterpret_cast<bf16x4*>(
            &vt[(size_t)((b * HEADS + h) * DKH + dk) * SEQ + tok]) = pk;
      } else {
#pragma unroll
        for (int j = 0; j < 4; ++j) {
          float v = acc[m][n][j] + bc;
          size_t idx = (size_t)(row0 + j) * N + col;
          if (EPI == 0) {
            ((__bf16*)Cout)[idx] = (__bf16)v;
          } else {
            ((float*)Cout)[idx] = v + resid[idx];
          }
        }
      }
    }
}

// ---------------- fp8 GEMM, MX-scaled K=128 MFMA, BK=128, SINGLE 24KB buffer ----------------
// A,B in e4m3. LDS 24KB; hint (256,4) -> natural VGPR 56, 4 blk/CU, no spill.
// r13 bank-conflict fix (confirmed: fp8 dispatches left the top-5): chunk j=2a+p stored at
// slot (a+4p)^(r&7) -> read slots l4^s7 and (l4^s7)^4, matching the proven bf16 pattern.
// EPI=0 (FC1): A unscaled, B x16 -> acc*0.0625, +bias, GELU, out = e4m3 x16 (bytes).
// EPI=1 (FC2): A x16, B x16 -> acc/256, +bias, +resid, out = fp32.
template <int EPI>
__global__ __launch_bounds__(256, 4) void gemm_fp8(const unsigned char* __restrict__ A,
                                                   const unsigned char* __restrict__ B,
                                                   const float* __restrict__ bias,
                                                   const float* __restrict__ resid,
                                                   void* __restrict__ Cout,
                                                   int M, int N, int K) {
  __shared__ unsigned char As[128 * 128];   // 16KB
  __shared__ unsigned char Bs[64 * 128];    // 8KB
  int tid = threadIdx.x;
  int bm = blockIdx.x, bn = blockIdx.y;
  int wid = tid >> 6, lane = tid & 63;
  int l15 = lane & 15, l4 = lane >> 4;
  int rowb = wid * 32;

  f32x4 acc[2][4] = {};

  // slot s of row r holds global chunk j = sigma^-1(s ^ (r&7)), sigma(2a+p)=a+4p.
  auto stage = [&](int kt) {
#pragma unroll
    for (int r = 0; r < 4; ++r) {       // A: 128 rows x 8 chunks = 1024
      int c0 = (r * 4 + wid) * 64;
      int c = c0 + lane;
      int row = c >> 3;
      int v = (c & 7) ^ (row & 7);
      int j = 2 * (v & 3) + (v >> 2);
      GLD16(&A[(size_t)(bm * 128 + row) * K + kt + j * 16], &As[c0 * 16]);
    }
#pragma unroll
    for (int r = 0; r < 2; ++r) {       // B: 64 rows x 8 chunks = 512
      int c0 = (r * 4 + wid) * 64;
      int c = c0 + lane;
      int row = c >> 3;
      int v = (c & 7) ^ (row & 7);
      int j = 2 * (v & 3) + (v >> 2);
      GLD16(&B[(size_t)(bn * 64 + row) * K + kt + j * 16], &Bs[c0 * 16]);
    }
  };

  // lane's 32 K-bytes (chunks 2*l4, 2*l4+1) live at slots l4^s7 and (l4^s7)^4.
  auto ld32 = [&](const unsigned char* base, int row) -> i32x8 {
    int off = (l4 ^ (l15 & 7)) * 16;
    i32x8 r;
    *reinterpret_cast<i32x4*>(&r) =
        *reinterpret_cast<const i32x4*>(&base[row * 128 + off]);
    *(reinterpret_cast<i32x4*>(&r) + 1) =
        *reinterpret_cast<const i32x4*>(&base[row * 128 + (off ^ 64)]);
    return r;
  };

  auto compute = [&]() {
    i32x8 af[2], bfr[4];
#pragma unroll
    for (int m = 0; m < 2; ++m) af[m] = ld32(As, rowb + m * 16 + l15);
#pragma unroll
    for (int n = 0; n < 4; ++n) bfr[n] = ld32(Bs, n * 16 + l15);
#pragma unroll
    for (int m = 0; m < 2; ++m)
#pragma unroll
      for (int n = 0; n < 4; ++n)
        acc[m][n] = __builtin_amdgcn_mfma_scale_f32_16x16x128_f8f6f4(
            af[m], bfr[n], acc[m][n], 0, 0,          // cbsz=0 (e4m3), blgp=0 (e4m3)
            0, 0x7F7F7F7F,                           // opsel_a, scale_a = 1.0 (e8m0 127)
            0, 0x7F7F7F7F);                          // opsel_b, scale_b = 1.0
  };

  for (int kt = 0; kt < K; kt += 128) {
    __syncthreads();               // WAR: all waves done reading previous tile
    stage(kt);
    __syncthreads();               // RAW: drains vmcnt -> tile landed for all waves
    compute();
  }

#pragma unroll
  for (int m = 0; m < 2; ++m)
#pragma unroll
    for (int n = 0; n < 4; ++n) {
      int row0 = bm * 128 + rowb + m * 16 + l4 * 4;
      int col = bn * 64 + n * 16 + l15;
      float bc = bias[col];
#pragma unroll
      for (int j = 0; j < 4; ++j) {
        if (EPI == 0) {
          float v = acc[m][n][j] * 0.0625f + bc;   // undo weight x16
          float z = 1.59576912f * (v + 0.044715f * v * v * v);
          float tt = __expf(fminf(z, 80.f));
          float g = v * __fdividef(tt, tt + 1.0f);
          // emit e4m3 x16 for the fp8 FC2 path (|g|<=~3 -> x16 <= 48 << 448 max)
          ((unsigned char*)Cout)[(size_t)(row0 + j) * N + col] =
              __hip_fp8_e4m3(g * 16.f).__x;
        } else {
          size_t idx = (size_t)(row0 + j) * N + col;
          ((float*)Cout)[idx] = acc[m][n][j] * (1.f / 256.f) + bc + resid[idx];
        }
      }
    }
}

// ---------------- flash attention: block-level LDS staging of K/V (r13-proven) ----------------
// r14 (Q-split) and r15 (paired KV tiles) both regressed: staging duplication and register
// spill respectively. This r13 version is the verified local optimum: 44us, VGPR 76, no spill.
__global__ __launch_bounds__(256, 3) void attn_kernel(const __bf16* __restrict__ qkv,
                                                      const __bf16* __restrict__ vt,
                                                      __bf16* __restrict__ out) {
  int bid = blockIdx.x;
  int xcd = bid & 7, kk0 = bid >> 3;     // 96 blocks per XCD
  int bh = (kk0 >> 3) * 8 + xcd;         // 12 heads per XCD
  int qt = kk0 & 7;
  int b = bh / HEADS, h = bh % HEADS;
  int tid = threadIdx.x, wid = tid >> 6, lane = tid & 63;
  int l15 = lane & 15, l4 = lane >> 4;
  int qr0 = qt * 128 + wid * 32;
  const size_t rs = 3 * DIM;
  const __bf16* Qb = qkv + (size_t)(b * SEQ) * rs + h * DKH;
  const __bf16* Kb = Qb + DIM;
  const __bf16* Vb = vt + (size_t)bh * DKH * SEQ;

  __shared__ __bf16 Ks[64 * 64];
  __shared__ __bf16 Vs[64 * 64];
  __shared__ __bf16 Ps[4][32][72];
  __bf16(*Psw)[72] = Ps[wid];

  bf16x8 qf[2][2];
#pragma unroll
  for (int m = 0; m < 2; ++m)
#pragma unroll
    for (int kc = 0; kc < 2; ++kc) {
      bf16x8 t = *reinterpret_cast<const bf16x8*>(
          &Qb[(size_t)(qr0 + m * 16 + l15) * rs + kc * 32 + l4 * 8]);
#pragma unroll
      for (int e = 0; e < 8; ++e) t[e] = (__bf16)((float)t[e] * 0.125f);
      qf[m][kc] = t;
    }

  f32x4 o[2][4] = {};
  f32x4 lsum[2] = {};

  for (int kv0 = 0; kv0 < SEQ; kv0 += 64) {
    __syncthreads();
#pragma unroll
    for (int cc = 0; cc < 2; ++cc) {
      int c0 = (wid * 2 + cc) * 64;
      int c = c0 + lane;
      int row = c >> 3;
      int sb = (c & 7) * 16;
      int pkc = sb ^ (((row >> 2) & 7) << 4);
      GLD16(&Kb[(size_t)(kv0 + row) * rs + (pkc >> 1)], &Ks[c0 * 8]);
      int pvc = sb ^ ((row & 7) << 4);
      GLD16(&Vb[(size_t)row * SEQ + kv0 + (pvc >> 1)], &Vs[c0 * 8]);
    }
    __syncthreads();

    bf16x8 kb[4][2];
#pragma unroll
    for (int nf = 0; nf < 4; ++nf)
#pragma unroll
      for (int kc = 0; kc < 2; ++kc) {
        int row = 4 * l15 + nf;
        int col = (kc * 64 + l4 * 16) ^ ((l15 & 7) << 4);
        kb[nf][kc] = *reinterpret_cast<const bf16x8*>(&Ks[row * 64 + (col >> 1)]);
      }
    f32x4 s[2][4] = {};
#pragma unroll
    for (int m = 0; m < 2; ++m)
#pragma unroll
      for (int nf = 0; nf < 4; ++nf)
#pragma unroll
        for (int kc = 0; kc < 2; ++kc)
          s[m][nf] = __builtin_amdgcn_mfma_f32_16x16x32_bf16(qf[m][kc], kb[nf][kc], s[m][nf], 0, 0, 0);

    bf16x8 vf[4][2];
#pragma unroll
    for (int d = 0; d < 4; ++d)
#pragma unroll
      for (int kc = 0; kc < 2; ++kc) {
        int row = d * 16 + l15;
        int col = (kc * 64 + l4 * 16) ^ ((l15 & 7) << 4);
        vf[d][kc] = *reinterpret_cast<const bf16x8*>(&Vs[row * 64 + (col >> 1)]);
      }

#pragma unroll
    for (int m = 0; m < 2; ++m)
#pragma unroll
      for (int j = 0; j < 4; ++j) {
        bf16x4 pk;
        float ss = 0.f;
#pragma unroll
        for (int nf = 0; nf < 4; ++nf) {
          float p = __expf(s[m][nf][j]);
          ss += p;
          pk[nf] = (__bf16)p;
        }
        lsum[m][j] += ss;
        *reinterpret_cast<bf16x4*>(&Psw[m * 16 + l4 * 4 + j][l15 * 4]) = pk;
      }
    asm volatile("s_waitcnt lgkmcnt(0)" ::: "memory");
    __builtin_amdgcn_sched_barrier(0);

    bf16x8 pf[2][2];
#pragma unroll
    for (int m = 0; m < 2; ++m)
#pragma unroll
      for (int kc = 0; kc < 2; ++kc)
        pf[m][kc] = *reinterpret_cast<const bf16x8*>(&Psw[m * 16 + l15][kc * 32 + l4 * 8]);
#pragma unroll
    for (int m = 0; m < 2; ++m)
#pragma unroll
      for (int d = 0; d < 4; ++d)
#pragma unroll
        for (int kc = 0; kc < 2; ++kc)
          o[m][d] = __builtin_amdgcn_mfma_f32_16x16x32_bf16(pf[m][kc], vf[d][kc], o[m][d], 0, 0, 0);
  }

#pragma unroll
  for (int off = 1; off < 16; off <<= 1)
#pragma unroll
    for (int m = 0; m < 2; ++m)
#pragma unroll
      for (int j = 0; j < 4; ++j) lsum[m][j] += __shfl_xor(lsum[m][j], off, 64);

  __bf16* op = out + (size_t)(b * SEQ) * DIM + h * DKH;
#pragma unroll
  for (int m = 0; m < 2; ++m)
#pragma unroll
    for (int j = 0; j < 4; ++j) {
      float rl = 1.f / lsum[m][j];
      int row = qr0 + m * 16 + l4 * 4 + j;
#pragma unroll
      for (int d = 0; d < 4; ++d)
        op[(size_t)row * DIM + d * 16 + l15] = (__bf16)(o[m][d][j] * rl);
    }
}

extern "C" void kernel_launch(void* const* d_in, const int* in_sizes, int n_in,
                              void* d_out, int out_size, void* d_ws, size_t ws_size,
                              hipStream_t stream) {
  const float* x      = (const float*)d_in[0];
  const float* ln1_w  = (const float*)d_in[1];
  const float* ln1_b  = (const float*)d_in[2];
  const float* qkv_w  = (const float*)d_in[3];
  const float* qkv_b  = (const float*)d_in[4];
  const float* proj_w = (const float*)d_in[5];
  const float* proj_b = (const float*)d_in[6];
  const float* ln2_w  = (const float*)d_in[7];
  const float* ln2_b  = (const float*)d_in[8];
  const float* fc1_w  = (const float*)d_in[9];
  const float* fc1_b  = (const float*)d_in[10];
  const float* fc2_w  = (const float*)d_in[11];
  const float* fc2_b  = (const float*)d_in[12];

  char* ws = (char*)d_ws;
  size_t o = 0;
  __bf16* qkvw_bf = (__bf16*)(ws + o); o += (size_t)3 * DIM * DIM * 2;
  __bf16* projw_bf = (__bf16*)(ws + o); o += (size_t)DIM * DIM * 2;
  unsigned char* fc1w_f8 = (unsigned char*)(ws + o); o += (size_t)DFF * DIM;
  unsigned char* fc2w_f8 = (unsigned char*)(ws + o); o += (size_t)DIM * DFF;
  __bf16* h_bf    = (__bf16*)(ws + o); o += (size_t)ROWS * DIM * 2;
  float*  x1      = (float*)(ws + o);  o += (size_t)ROWS * DIM * 4;
  __bf16* qkv_bf  = (__bf16*)(ws + o); o += (size_t)ROWS * 3 * DIM * 2;
  __bf16* attn_bf = (__bf16*)(ws + o); o += (size_t)ROWS * DIM * 2;
  unsigned char* ff_f8 = (unsigned char*)qkv_bf;  // FC1 fp8 out aliases dead qkv region
  __bf16* vtp     = (__bf16*)x1;                  // V^T aliases x1 (dead until proj writes it)
  unsigned char* h_f8 = (unsigned char*)h_bf;     // LN2 fp8 out reuses h (LN1 out dead by then)

  // 1. weights (qkv/proj -> bf16, fc1/fc2 -> fp8 x16)
  cvt4_kernel<<<2048, 256, 0, stream>>>(
      qkv_w, 3 * DIM * DIM / 4, proj_w, DIM * DIM / 4,
      fc1_w, DFF * DIM / 4, fc2_w, DIM * DFF / 4,
      qkvw_bf, projw_bf, fc1w_f8, fc2w_f8);

  // 2. LN1
  ln_kernel<<<ROWS / 4, 256, 0, stream>>>(x, ln1_w, ln1_b, h_bf);
  // 3. QKV = h @ qkv_w^T + b   (V stored transposed into vtp)
  gemm_nt<0, 64, 0><<<dim3(ROWS / 128, 3 * DIM / 64), 256, 0, stream>>>(
      h_bf, qkvw_bf, qkv_b, nullptr, vtp, qkv_bf, ROWS, 3 * DIM, DIM);
  // 4. attention (768 XCD-swizzled blocks)
  attn_kernel<<<dim3(8 * BATCH * HEADS), 256, 0, stream>>>(qkv_bf, vtp, attn_bf);
  // 5. x1 = x + attn @ proj_w^T + b
  gemm_nt<2, 64, 0><<<dim3(ROWS / 128, DIM / 64), 256, 0, stream>>>(
      attn_bf, projw_bf, proj_b, x, nullptr, x1, ROWS, DIM, DIM);
  // 6. LN2 -> fp8
  ln_f8_kernel<<<ROWS / 4, 256, 0, stream>>>(x1, ln2_w, ln2_b, h_f8);
  // 7. ff = gelu(h2 @ fc1_w^T + b) -> e4m3 x16  (fp8 MX path, BK=128)
  gemm_fp8<0><<<dim3(ROWS / 128, DFF / 64), 256, 0, stream>>>(
      h_f8, fc1w_f8, fc1_b, nullptr, ff_f8, ROWS, DFF, DIM);
  // 8. out = x1 + ff @ fc2_w^T + b  (fp8 MX path, K=3072, 24 K-steps)
  gemm_fp8<1><<<dim3(ROWS / 128, DIM / 64), 256, 0, stream>>>(
      ff_f8, fc2w_f8, fc2_b, x1, (float*)d_out, ROWS, DIM, DFF);
}

// Round 18
// 180.803 us; speedup vs baseline: 1.0821x; 1.0048x over previous
//
#include <hip/hip_runtime.h>
#include <hip/hip_bf16.h>
#include <hip/hip_fp8.h>
#include <math.h>

typedef __attribute__((ext_vector_type(8))) __bf16 bf16x8;
typedef __attribute__((ext_vector_type(4))) __bf16 bf16x4;
typedef __attribute__((ext_vector_type(4))) float f32x4;
typedef __attribute__((ext_vector_type(4))) int i32x4;
typedef __attribute__((ext_vector_type(8))) int i32x8;

#define DIM 768
#define DFF 3072
#define HEADS 12
#define DKH 64
#define SEQ 1024
#define BATCH 8
#define ROWS (SEQ * BATCH)

#define GLD16(gp, lp)                                                      \
  __builtin_amdgcn_global_load_lds(                                        \
      (const __attribute__((address_space(1))) void*)(gp),                 \
      (__attribute__((address_space(3))) void*)(lp), 16, 0, 0)

__device__ __forceinline__ unsigned int pack4_e4m3(float a, float b, float c, float d) {
  __hip_fp8_e4m3 q0(a), q1(b), q2(c), q3(d);
  return (unsigned int)q0.__x | ((unsigned int)q1.__x << 8) |
         ((unsigned int)q2.__x << 16) | ((unsigned int)q3.__x << 24);
}

// ------- weight convert: qkv/proj -> bf16, fc1/fc2 -> fp8 e4m3 x16 -------
__global__ __launch_bounds__(256) void cvt4_kernel(const float* __restrict__ s0, int n0,
                                                   const float* __restrict__ s1, int n1,
                                                   const float* __restrict__ s2, int n2,
                                                   const float* __restrict__ s3, int n3,
                                                   __bf16* __restrict__ d0,
                                                   __bf16* __restrict__ d1,
                                                   unsigned char* __restrict__ d2,
                                                   unsigned char* __restrict__ d3) {
  int i0 = blockIdx.x * 256 + threadIdx.x;
  int st = gridDim.x * 256;
  const float* bsrc[2] = {s0, s1};
  __bf16* bdst[2] = {d0, d1};
  int bns[2] = {n0, n1};
#pragma unroll
  for (int t = 0; t < 2; ++t) {
    const f32x4* in = reinterpret_cast<const f32x4*>(bsrc[t]);
    bf16x4* out = reinterpret_cast<bf16x4*>(bdst[t]);
    for (int i = i0; i < bns[t]; i += st) {
      f32x4 v = in[i];
      bf16x4 o;
#pragma unroll
      for (int j = 0; j < 4; ++j) o[j] = (__bf16)v[j];
      out[i] = o;
    }
  }
  const float* fsrc[2] = {s2, s3};
  unsigned char* fdst[2] = {d2, d3};
  int fns[2] = {n2, n3};
#pragma unroll
  for (int t = 0; t < 2; ++t) {  // fp8 x16 (keeps weights out of e4m3 subnormal range)
    const f32x4* in = reinterpret_cast<const f32x4*>(fsrc[t]);
    unsigned int* out = reinterpret_cast<unsigned int*>(fdst[t]);
    for (int i = i0; i < fns[t]; i += st) {
      f32x4 v = in[i];
      out[i] = pack4_e4m3(v[0] * 16.f, v[1] * 16.f, v[2] * 16.f, v[3] * 16.f);
    }
  }
}

// ---------------- layernorm: fp32 in -> bf16 out (1 wave / row) ----------------
__global__ __launch_bounds__(256) void ln_kernel(const float* __restrict__ x,
                                                 const float* __restrict__ w,
                                                 const float* __restrict__ b,
                                                 __bf16* __restrict__ out) {
  int wid = threadIdx.x >> 6, lane = threadIdx.x & 63;
  int row = blockIdx.x * 4 + wid;
  const f32x4* xp = reinterpret_cast<const f32x4*>(x + (size_t)row * DIM);
  f32x4 v[3];
  float s1 = 0.f, s2 = 0.f;
#pragma unroll
  for (int i = 0; i < 3; ++i) {
    v[i] = xp[lane + i * 64];
#pragma unroll
    for (int c = 0; c < 4; ++c) { s1 += v[i][c]; s2 += v[i][c] * v[i][c]; }
  }
#pragma unroll
  for (int off = 1; off < 64; off <<= 1) {
    s1 += __shfl_xor(s1, off, 64);
    s2 += __shfl_xor(s2, off, 64);
  }
  float mu = s1 * (1.f / DIM);
  float var = s2 * (1.f / DIM) - mu * mu;
  float rs = rsqrtf(var + 1e-5f);
  const f32x4* wp = reinterpret_cast<const f32x4*>(w);
  const f32x4* bp = reinterpret_cast<const f32x4*>(b);
  __bf16* op = out + (size_t)row * DIM;
#pragma unroll
  for (int i = 0; i < 3; ++i) {
    int c4 = lane + i * 64;
    f32x4 wv = wp[c4], bv = bp[c4];
    bf16x4 ov;
#pragma unroll
    for (int c = 0; c < 4; ++c) ov[c] = (__bf16)((v[i][c] - mu) * rs * wv[c] + bv[c]);
    *reinterpret_cast<bf16x4*>(&op[c4 * 4]) = ov;
  }
}

// ---------------- layernorm: fp32 in -> fp8 e4m3 out (for FC1's fp8 path) ----------------
__global__ __launch_bounds__(256) void ln_f8_kernel(const float* __restrict__ x,
                                                    const float* __restrict__ w,
                                                    const float* __restrict__ b,
                                                    unsigned char* __restrict__ out) {
  int wid = threadIdx.x >> 6, lane = threadIdx.x & 63;
  int row = blockIdx.x * 4 + wid;
  const f32x4* xp = reinterpret_cast<const f32x4*>(x + (size_t)row * DIM);
  f32x4 v[3];
  float s1 = 0.f, s2 = 0.f;
#pragma unroll
  for (int i = 0; i < 3; ++i) {
    v[i] = xp[lane + i * 64];
#pragma unroll
    for (int c = 0; c < 4; ++c) { s1 += v[i][c]; s2 += v[i][c] * v[i][c]; }
  }
#pragma unroll
  for (int off = 1; off < 64; off <<= 1) {
    s1 += __shfl_xor(s1, off, 64);
    s2 += __shfl_xor(s2, off, 64);
  }
  float mu = s1 * (1.f / DIM);
  float var = s2 * (1.f / DIM) - mu * mu;
  float rs = rsqrtf(var + 1e-5f);
  const f32x4* wp = reinterpret_cast<const f32x4*>(w);
  const f32x4* bp = reinterpret_cast<const f32x4*>(b);
  unsigned int* op = reinterpret_cast<unsigned int*>(out + (size_t)row * DIM);
#pragma unroll
  for (int i = 0; i < 3; ++i) {
    int c4 = lane + i * 64;
    f32x4 wv = wp[c4], bv = bp[c4];
    float o0 = (v[i][0] - mu) * rs * wv[0] + bv[0];
    float o1 = (v[i][1] - mu) * rs * wv[1] + bv[1];
    float o2 = (v[i][2] - mu) * rs * wv[2] + bv[2];
    float o3 = (v[i][3] - mu) * rs * wv[3] + bv[3];
    op[c4] = pack4_e4m3(o0, o1, o2, o3);
  }
}

// ---------------- NT GEMM: BN=64, SINGLE 24KB buffer (m97 structure) -> 4 blocks/CU ---------
// r9-proven config. Hint (256,4): VGPR cap 128 >= natural 68 -> no squeeze.
// r10/r12 lesson: ANY waves/EU hint > 4 at 256 threads forces sub-natural VGPR and spills.
// No setprio here: m190/our-r2 evidence says it is null-to-negative on barrier-lockstep GEMMs.
template <int EPI, int BN, int DBUF>
__global__ __launch_bounds__(256, 4) void gemm_nt(const __bf16* __restrict__ A,
                                                  const __bf16* __restrict__ B,
                                                  const float* __restrict__ bias,
                                                  const float* __restrict__ resid,
                                                  __bf16* __restrict__ vt,
                                                  void* __restrict__ Cout,
                                                  int M, int N, int K) {
  constexpr int NBUF = DBUF ? 2 : 1;
  constexpr int MF = (BN == 128) ? 4 : 2;
  static_assert(BN == 64, "geometry assumes BN=64");
  __shared__ __bf16 As[NBUF * 128 * 64];
  __shared__ __bf16 Bs[NBUF * BN * 64];
  int tid = threadIdx.x;
  int bm = blockIdx.x, bn = blockIdx.y;
  int wid = tid >> 6, lane = tid & 63;
  int l15 = lane & 15, l4 = lane >> 4;
  int rowb = wid * 32;
  int colb = 0;

  f32x4 acc[MF][4] = {};

  auto stage = [&](int buf, int kt) {
    __bf16* Ab = As + buf * 128 * 64;
    __bf16* Bb = Bs + buf * BN * 64;
#pragma unroll
    for (int r = 0; r < 4; ++r) {
      int c0 = (r * 4 + wid) * 64;
      int c = c0 + lane;
      int row = c >> 3;
      int colE = ((c & 7) ^ (row & 7)) * 8;
      GLD16(&A[(size_t)(bm * 128 + row) * K + kt + colE], &Ab[c0 * 8]);
    }
#pragma unroll
    for (int r = 0; r < BN / 32; ++r) {
      int c0 = (r * 4 + wid) * 64;
      int c = c0 + lane;
      int row = c >> 3;
      int colE = ((c & 7) ^ (row & 7)) * 8;
      GLD16(&B[(size_t)(bn * BN + row) * K + kt + colE], &Bb[c0 * 8]);
    }
  };

  auto compute = [&](int buf) {
    const __bf16* Ab = As + buf * 128 * 64;
    const __bf16* Bb = Bs + buf * BN * 64;
#pragma unroll
    for (int kc = 0; kc < 2; ++kc) {
      int cswz = ((kc * 4 + l4) ^ (l15 & 7)) * 8;
      bf16x8 af[MF], bfr[4];
#pragma unroll
      for (int m = 0; m < MF; ++m)
        af[m] = *reinterpret_cast<const bf16x8*>(&Ab[(rowb + m * 16 + l15) * 64 + cswz]);
#pragma unroll
      for (int n = 0; n < 4; ++n)
        bfr[n] = *reinterpret_cast<const bf16x8*>(&Bb[(colb + n * 16 + l15) * 64 + cswz]);
#pragma unroll
      for (int m = 0; m < MF; ++m)
#pragma unroll
        for (int n = 0; n < 4; ++n)
          acc[m][n] = __builtin_amdgcn_mfma_f32_16x16x32_bf16(af[m], bfr[n], acc[m][n], 0, 0, 0);
    }
  };

  if constexpr (DBUF) {
    stage(0, 0);
    int cur = 0;
    for (int kt = 0; kt < K; kt += 64) {
      if (kt + 64 < K) {
        stage(cur ^ 1, kt + 64);
        asm volatile("s_waitcnt vmcnt(6)" ::: "memory");
      } else {
        asm volatile("s_waitcnt vmcnt(0)" ::: "memory");
      }
      __builtin_amdgcn_s_barrier();
      compute(cur);
      asm volatile("s_waitcnt lgkmcnt(0)" ::: "memory");
      __builtin_amdgcn_s_barrier();
      cur ^= 1;
    }
  } else {
    // m97 single-buffer loop: __syncthreads drains vmcnt/lgkm (RAW + WAR).
    for (int kt = 0; kt < K; kt += 64) {
      __syncthreads();
      stage(0, kt);
      __syncthreads();
      compute(0);
    }
  }

#pragma unroll
  for (int m = 0; m < MF; ++m)
#pragma unroll
    for (int n = 0; n < 4; ++n) {
      int row0 = bm * 128 + rowb + m * 16 + l4 * 4;
      int col = bn * BN + colb + n * 16 + l15;
      float bc = bias[col];
      if (EPI == 0 && col >= 2 * DIM) {
        int h = (col - 2 * DIM) >> 6, dk = (col - 2 * DIM) & 63;
        int b = row0 >> 10, tok = row0 & 1023;
        bf16x4 pk;
#pragma unroll
        for (int j = 0; j < 4; ++j) pk[j] = (__bf16)(acc[m][n][j] + bc);
        *reinterpret_cast<bf16x4*>(
            &vt[(size_t)((b * HEADS + h) * DKH + dk) * SEQ + tok]) = pk;
      } else {
#pragma unroll
        for (int j = 0; j < 4; ++j) {
          float v = acc[m][n][j] + bc;
          size_t idx = (size_t)(row0 + j) * N + col;
          if (EPI == 0) {
            ((__bf16*)Cout)[idx] = (__bf16)v;
          } else {
            ((float*)Cout)[idx] = v + resid[idx];
          }
        }
      }
    }
}

// ---------------- fp8 GEMM, MX-scaled K=128 MFMA, BK=128, SINGLE 24KB buffer ----------------
// A,B in e4m3. LDS 24KB; hint (256,4) -> natural VGPR 56, 4 blk/CU, no spill.
// r13 bank-conflict fix (confirmed): chunk j=2a+p stored at slot (a+4p)^(r&7) -> read slots
// l4^s7 and (l4^s7)^4, matching the proven bf16 pattern. fp8 dispatches left the top-5.
// EPI=0 (FC1): A unscaled, B x16 -> acc*0.0625, +bias, GELU, out = e4m3 x16 (bytes).
// EPI=1 (FC2): A x16, B x16 -> acc/256, +bias, +resid, out = fp32.
template <int EPI>
__global__ __launch_bounds__(256, 4) void gemm_fp8(const unsigned char* __restrict__ A,
                                                   const unsigned char* __restrict__ B,
                                                   const float* __restrict__ bias,
                                                   const float* __restrict__ resid,
                                                   void* __restrict__ Cout,
                                                   int M, int N, int K) {
  __shared__ unsigned char As[128 * 128];   // 16KB
  __shared__ unsigned char Bs[64 * 128];    // 8KB
  int tid = threadIdx.x;
  int bm = blockIdx.x, bn = blockIdx.y;
  int wid = tid >> 6, lane = tid & 63;
  int l15 = lane & 15, l4 = lane >> 4;
  int rowb = wid * 32;

  f32x4 acc[2][4] = {};

  // slot s of row r holds global chunk j = sigma^-1(s ^ (r&7)), sigma(2a+p)=a+4p.
  auto stage = [&](int kt) {
#pragma unroll
    for (int r = 0; r < 4; ++r) {       // A: 128 rows x 8 chunks = 1024
      int c0 = (r * 4 + wid) * 64;
      int c = c0 + lane;
      int row = c >> 3;
      int v = (c & 7) ^ (row & 7);
      int j = 2 * (v & 3) + (v >> 2);
      GLD16(&A[(size_t)(bm * 128 + row) * K + kt + j * 16], &As[c0 * 16]);
    }
#pragma unroll
    for (int r = 0; r < 2; ++r) {       // B: 64 rows x 8 chunks = 512
      int c0 = (r * 4 + wid) * 64;
      int c = c0 + lane;
      int row = c >> 3;
      int v = (c & 7) ^ (row & 7);
      int j = 2 * (v & 3) + (v >> 2);
      GLD16(&B[(size_t)(bn * 64 + row) * K + kt + j * 16], &Bs[c0 * 16]);
    }
  };

  // lane's 32 K-bytes (chunks 2*l4, 2*l4+1) live at slots l4^s7 and (l4^s7)^4.
  auto ld32 = [&](const unsigned char* base, int row) -> i32x8 {
    int off = (l4 ^ (l15 & 7)) * 16;
    i32x8 r;
    *reinterpret_cast<i32x4*>(&r) =
        *reinterpret_cast<const i32x4*>(&base[row * 128 + off]);
    *(reinterpret_cast<i32x4*>(&r) + 1) =
        *reinterpret_cast<const i32x4*>(&base[row * 128 + (off ^ 64)]);
    return r;
  };

  auto compute = [&]() {
    i32x8 af[2], bfr[4];
#pragma unroll
    for (int m = 0; m < 2; ++m) af[m] = ld32(As, rowb + m * 16 + l15);
#pragma unroll
    for (int n = 0; n < 4; ++n) bfr[n] = ld32(Bs, n * 16 + l15);
#pragma unroll
    for (int m = 0; m < 2; ++m)
#pragma unroll
      for (int n = 0; n < 4; ++n)
        acc[m][n] = __builtin_amdgcn_mfma_scale_f32_16x16x128_f8f6f4(
            af[m], bfr[n], acc[m][n], 0, 0,          // cbsz=0 (e4m3), blgp=0 (e4m3)
            0, 0x7F7F7F7F,                           // opsel_a, scale_a = 1.0 (e8m0 127)
            0, 0x7F7F7F7F);                          // opsel_b, scale_b = 1.0
  };

  for (int kt = 0; kt < K; kt += 128) {
    __syncthreads();               // WAR: all waves done reading previous tile
    stage(kt);
    __syncthreads();               // RAW: drains vmcnt -> tile landed for all waves
    compute();
  }

#pragma unroll
  for (int m = 0; m < 2; ++m)
#pragma unroll
    for (int n = 0; n < 4; ++n) {
      int row0 = bm * 128 + rowb + m * 16 + l4 * 4;
      int col = bn * 64 + n * 16 + l15;
      float bc = bias[col];
#pragma unroll
      for (int j = 0; j < 4; ++j) {
        if (EPI == 0) {
          float v = acc[m][n][j] * 0.0625f + bc;   // undo weight x16
          float z = 1.59576912f * (v + 0.044715f * v * v * v);
          float tt = __expf(fminf(z, 80.f));
          float g = v * __fdividef(tt, tt + 1.0f);
          // emit e4m3 x16 for the fp8 FC2 path (|g|<=~3 -> x16 <= 48 << 448 max)
          ((unsigned char*)Cout)[(size_t)(row0 + j) * N + col] =
              __hip_fp8_e4m3(g * 16.f).__x;
        } else {
          size_t idx = (size_t)(row0 + j) * N + col;
          ((float*)Cout)[idx] = acc[m][n][j] * (1.f / 256.f) + bc + resid[idx];
        }
      }
    }
}

// ---------------- flash attention: r13 structure + T5 setprio around MFMA clusters ----------
// r17: the only untried documented lever for this shape. m191 measured +4-7% for setprio on
// attn kernels whose independent blocks co-reside at different phases (our case: 3 blk/CU,
// each cycling stage->QK->softmax->PV out of phase); m190 says null on lockstep GEMMs, so
// the GEMMs stay untouched. Zero layout/resource change; trivially revertible.
__global__ __launch_bounds__(256, 3) void attn_kernel(const __bf16* __restrict__ qkv,
                                                      const __bf16* __restrict__ vt,
                                                      __bf16* __restrict__ out) {
  int bid = blockIdx.x;
  int xcd = bid & 7, kk0 = bid >> 3;     // 96 blocks per XCD
  int bh = (kk0 >> 3) * 8 + xcd;         // 12 heads per XCD
  int qt = kk0 & 7;
  int b = bh / HEADS, h = bh % HEADS;
  int tid = threadIdx.x, wid = tid >> 6, lane = tid & 63;
  int l15 = lane & 15, l4 = lane >> 4;
  int qr0 = qt * 128 + wid * 32;
  const size_t rs = 3 * DIM;
  const __bf16* Qb = qkv + (size_t)(b * SEQ) * rs + h * DKH;
  const __bf16* Kb = Qb + DIM;
  const __bf16* Vb = vt + (size_t)bh * DKH * SEQ;

  __shared__ __bf16 Ks[64 * 64];
  __shared__ __bf16 Vs[64 * 64];
  __shared__ __bf16 Ps[4][32][72];
  __bf16(*Psw)[72] = Ps[wid];

  bf16x8 qf[2][2];
#pragma unroll
  for (int m = 0; m < 2; ++m)
#pragma unroll
    for (int kc = 0; kc < 2; ++kc) {
      bf16x8 t = *reinterpret_cast<const bf16x8*>(
          &Qb[(size_t)(qr0 + m * 16 + l15) * rs + kc * 32 + l4 * 8]);
#pragma unroll
      for (int e = 0; e < 8; ++e) t[e] = (__bf16)((float)t[e] * 0.125f);
      qf[m][kc] = t;
    }

  f32x4 o[2][4] = {};
  f32x4 lsum[2] = {};

  for (int kv0 = 0; kv0 < SEQ; kv0 += 64) {
    __syncthreads();
#pragma unroll
    for (int cc = 0; cc < 2; ++cc) {
      int c0 = (wid * 2 + cc) * 64;
      int c = c0 + lane;
      int row = c >> 3;
      int sb = (c & 7) * 16;
      int pkc = sb ^ (((row >> 2) & 7) << 4);
      GLD16(&Kb[(size_t)(kv0 + row) * rs + (pkc >> 1)], &Ks[c0 * 8]);
      int pvc = sb ^ ((row & 7) << 4);
      GLD16(&Vb[(size_t)row * SEQ + kv0 + (pvc >> 1)], &Vs[c0 * 8]);
    }
    __syncthreads();

    bf16x8 kb[4][2];
#pragma unroll
    for (int nf = 0; nf < 4; ++nf)
#pragma unroll
      for (int kc = 0; kc < 2; ++kc) {
        int row = 4 * l15 + nf;
        int col = (kc * 64 + l4 * 16) ^ ((l15 & 7) << 4);
        kb[nf][kc] = *reinterpret_cast<const bf16x8*>(&Ks[row * 64 + (col >> 1)]);
      }
    f32x4 s[2][4] = {};
    __builtin_amdgcn_s_setprio(1);
#pragma unroll
    for (int m = 0; m < 2; ++m)
#pragma unroll
      for (int nf = 0; nf < 4; ++nf)
#pragma unroll
        for (int kc = 0; kc < 2; ++kc)
          s[m][nf] = __builtin_amdgcn_mfma_f32_16x16x32_bf16(qf[m][kc], kb[nf][kc], s[m][nf], 0, 0, 0);
    __builtin_amdgcn_s_setprio(0);

    bf16x8 vf[4][2];
#pragma unroll
    for (int d = 0; d < 4; ++d)
#pragma unroll
      for (int kc = 0; kc < 2; ++kc) {
        int row = d * 16 + l15;
        int col = (kc * 64 + l4 * 16) ^ ((l15 & 7) << 4);
        vf[d][kc] = *reinterpret_cast<const bf16x8*>(&Vs[row * 64 + (col >> 1)]);
      }

#pragma unroll
    for (int m = 0; m < 2; ++m)
#pragma unroll
      for (int j = 0; j < 4; ++j) {
        bf16x4 pk;
        float ss = 0.f;
#pragma unroll
        for (int nf = 0; nf < 4; ++nf) {
          float p = __expf(s[m][nf][j]);
          ss += p;
          pk[nf] = (__bf16)p;
        }
        lsum[m][j] += ss;
        *reinterpret_cast<bf16x4*>(&Psw[m * 16 + l4 * 4 + j][l15 * 4]) = pk;
      }
    asm volatile("s_waitcnt lgkmcnt(0)" ::: "memory");
    __builtin_amdgcn_sched_barrier(0);

    bf16x8 pf[2][2];
#pragma unroll
    for (int m = 0; m < 2; ++m)
#pragma unroll
      for (int kc = 0; kc < 2; ++kc)
        pf[m][kc] = *reinterpret_cast<const bf16x8*>(&Psw[m * 16 + l15][kc * 32 + l4 * 8]);
    __builtin_amdgcn_s_setprio(1);
#pragma unroll
    for (int m = 0; m < 2; ++m)
#pragma unroll
      for (int d = 0; d < 4; ++d)
#pragma unroll
        for (int kc = 0; kc < 2; ++kc)
          o[m][d] = __builtin_amdgcn_mfma_f32_16x16x32_bf16(pf[m][kc], vf[d][kc], o[m][d], 0, 0, 0);
    __builtin_amdgcn_s_setprio(0);
  }

#pragma unroll
  for (int off = 1; off < 16; off <<= 1)
#pragma unroll
    for (int m = 0; m < 2; ++m)
#pragma unroll
      for (int j = 0; j < 4; ++j) lsum[m][j] += __shfl_xor(lsum[m][j], off, 64);

  __bf16* op = out + (size_t)(b * SEQ) * DIM + h * DKH;
#pragma unroll
  for (int m = 0; m < 2; ++m)
#pragma unroll
    for (int j = 0; j < 4; ++j) {
      float rl = 1.f / lsum[m][j];
      int row = qr0 + m * 16 + l4 * 4 + j;
#pragma unroll
      for (int d = 0; d < 4; ++d)
        op[(size_t)row * DIM + d * 16 + l15] = (__bf16)(o[m][d][j] * rl);
    }
}

extern "C" void kernel_launch(void* const* d_in, const int* in_sizes, int n_in,
                              void* d_out, int out_size, void* d_ws, size_t ws_size,
                              hipStream_t stream) {
  const float* x      = (const float*)d_in[0];
  const float* ln1_w  = (const float*)d_in[1];
  const float* ln1_b  = (const float*)d_in[2];
  const float* qkv_w  = (const float*)d_in[3];
  const float* qkv_b  = (const float*)d_in[4];
  const float* proj_w = (const float*)d_in[5];
  const float* proj_b = (const float*)d_in[6];
  const float* ln2_w  = (const float*)d_in[7];
  const float* ln2_b  = (const float*)d_in[8];
  const float* fc1_w  = (const float*)d_in[9];
  const float* fc1_b  = (const float*)d_in[10];
  const float* fc2_w  = (const float*)d_in[11];
  const float* fc2_b  = (const float*)d_in[12];

  char* ws = (char*)d_ws;
  size_t o = 0;
  __bf16* qkvw_bf = (__bf16*)(ws + o); o += (size_t)3 * DIM * DIM * 2;
  __bf16* projw_bf = (__bf16*)(ws + o); o += (size_t)DIM * DIM * 2;
  unsigned char* fc1w_f8 = (unsigned char*)(ws + o); o += (size_t)DFF * DIM;
  unsigned char* fc2w_f8 = (unsigned char*)(ws + o); o += (size_t)DIM * DFF;
  __bf16* h_bf    = (__bf16*)(ws + o); o += (size_t)ROWS * DIM * 2;
  float*  x1      = (float*)(ws + o);  o += (size_t)ROWS * DIM * 4;
  __bf16* qkv_bf  = (__bf16*)(ws + o); o += (size_t)ROWS * 3 * DIM * 2;
  __bf16* attn_bf = (__bf16*)(ws + o); o += (size_t)ROWS * DIM * 2;
  unsigned char* ff_f8 = (unsigned char*)qkv_bf;  // FC1 fp8 out aliases dead qkv region
  __bf16* vtp     = (__bf16*)x1;                  // V^T aliases x1 (dead until proj writes it)
  unsigned char* h_f8 = (unsigned char*)h_bf;     // LN2 fp8 out reuses h (LN1 out dead by then)

  // 1. weights (qkv/proj -> bf16, fc1/fc2 -> fp8 x16)
  cvt4_kernel<<<2048, 256, 0, stream>>>(
      qkv_w, 3 * DIM * DIM / 4, proj_w, DIM * DIM / 4,
      fc1_w, DFF * DIM / 4, fc2_w, DIM * DFF / 4,
      qkvw_bf, projw_bf, fc1w_f8, fc2w_f8);

  // 2. LN1
  ln_kernel<<<ROWS / 4, 256, 0, stream>>>(x, ln1_w, ln1_b, h_bf);
  // 3. QKV = h @ qkv_w^T + b   (V stored transposed into vtp)
  gemm_nt<0, 64, 0><<<dim3(ROWS / 128, 3 * DIM / 64), 256, 0, stream>>>(
      h_bf, qkvw_bf, qkv_b, nullptr, vtp, qkv_bf, ROWS, 3 * DIM, DIM);
  // 4. attention (768 XCD-swizzled blocks)
  attn_kernel<<<dim3(8 * BATCH * HEADS), 256, 0, stream>>>(qkv_bf, vtp, attn_bf);
  // 5. x1 = x + attn @ proj_w^T + b
  gemm_nt<2, 64, 0><<<dim3(ROWS / 128, DIM / 64), 256, 0, stream>>>(
      attn_bf, projw_bf, proj_b, x, nullptr, x1, ROWS, DIM, DIM);
  // 6. LN2 -> fp8
  ln_f8_kernel<<<ROWS / 4, 256, 0, stream>>>(x1, ln2_w, ln2_b, h_f8);
  // 7. ff = gelu(h2 @ fc1_w^T + b) -> e4m3 x16  (fp8 MX path, BK=128)
  gemm_fp8<0><<<dim3(ROWS / 128, DFF / 64), 256, 0, stream>>>(
      h_f8, fc1w_f8, fc1_b, nullptr, ff_f8, ROWS, DFF, DIM);
  // 8. out = x1 + ff @ fc2_w^T + b  (fp8 MX path, K=3072, 24 K-steps)
  gemm_fp8<1><<<dim3(ROWS / 128, DIM / 64), 256, 0, stream>>>(
      ff_f8, fc2w_f8, fc2_b, x1, (float*)d_out, ROWS, DIM, DFF);
}